// Round 4
// baseline (192.526 us; speedup 1.0000x reference)
//
#include <hip/hip_runtime.h>
#include <math.h>

// SoftCodebook fused kernel v6 for MI355X (gfx950).
// p = softmax( (h/||h||) @ (proto/||proto||)^T / 0.1 ),  z = p @ proto
// v6: re-grained for latency hiding. Evidence from v2-v5: duration ~64us flat
// across radically different structures, nothing saturated -> per-wave serial
// VMEM chain (~250 ops) == kernel time, single residency round, no TLP.
// New decomposition: 16-row blocks (grid 4096), 4 waves split the K dimension:
//   wave w: sim t-tiles {2w,2w+1} (32 of 128 cols) + z dt-tiles {4w..4w+3}.
// Per-wave VMEM ~74 ops (4x shorter chain), total MFMA unchanged, 16 blocks/CU
// of work in ~4 residency rounds -> stalls of one round hidden by the next.
// Softmax across waves via one-barrier LSE merge (partial max+sum in LDS,
// exp2 rescale; exact same math, different summation order).

#define EPS 1e-12f
#define TAU_INV 10.0f

typedef _Float16 f16x8 __attribute__((ext_vector_type(8)));
typedef float f32x4 __attribute__((ext_vector_type(4)));

#define PB_STRIDE 136   // halves per pbuf row: 272 B = 16*17 (16B-aligned rows)

// ---------------------------------------------------------------------------
// k_prep: per-prototype L2 norm -> scale[128].  grid 128 x 64.
__global__ void k_prep(const float* __restrict__ proto, float* __restrict__ scale) {
    const int kp = blockIdx.x;
    const int lane = threadIdx.x;
    const float4 v = ((const float4*)(proto + kp * 256))[lane];
    float s = v.x * v.x + v.y * v.y + v.z * v.z + v.w * v.w;
    #pragma unroll
    for (int msk = 1; msk < 64; msk <<= 1) s += __shfl_xor(s, msk, 64);
    if (lane == 0) scale[kp] = fmaxf(sqrtf(s), EPS);
}

// ---------------------------------------------------------------------------
// k_frag: build per-lane B-fragment images (f16 cbar) in ws.  grid 128 x 64.
//   simB[(t*8+c)*64 + lane][j] = cbar[t*16+m][c*32+q*8+j]   (sim B operand)
//   zB [(dt*4+kc)*64 + lane][j] = cbar[kc*32+q*8+j][dt*16+m] (z  B operand)
// where m = lane&15, q = lane>>4 (matches mfma_f32_16x16x32_f16 B layout).
__global__ void k_frag(const float* __restrict__ proto,
                       const float* __restrict__ scale,
                       _Float16* __restrict__ simB, _Float16* __restrict__ zB) {
    const int b = blockIdx.x;
    const int lane = threadIdx.x;
    const int m = lane & 15, q = lane >> 4;
    _Float16 r[8];
    if (b < 64) {
        const int t = b >> 3, c = b & 7;
        const int kp = t * 16 + m;
        const float inv = 1.0f / scale[kp];
        const float* src = proto + (size_t)kp * 256 + c * 32 + q * 8;
        #pragma unroll
        for (int j = 0; j < 8; j++) r[j] = (_Float16)(src[j] * inv);
        *(f16x8*)(simB + ((size_t)b * 64 + lane) * 8) = *(const f16x8*)r;
    } else {
        const int b2 = b - 64;
        const int dt = b2 >> 2, kc = b2 & 3;
        #pragma unroll
        for (int j = 0; j < 8; j++) {
            const int kk = kc * 32 + q * 8 + j;
            r[j] = (_Float16)(proto[(size_t)kk * 256 + dt * 16 + m] / scale[kk]);
        }
        *(f16x8*)(zB + ((size_t)b2 * 64 + lane) * 8) = *(const f16x8*)r;
    }
}

// ---------------------------------------------------------------------------
// k_main: 256 threads = 4 waves on ONE 16-row tile, grid = M/16 = 4096.
__global__ __launch_bounds__(256) void k_main(
    const float* __restrict__ h,
    const float* __restrict__ scale,
    const _Float16* __restrict__ simB,
    const _Float16* __restrict__ zB,
    float* __restrict__ out_p,
    float* __restrict__ out_z) {

    __shared__ _Float16 pbuf[16 * PB_STRIDE];   // 4352 B
    __shared__ float pmx[4][16];                // per-wave partial max
    __shared__ float psum[4][16];               // per-wave partial sum

    const int tid = threadIdx.x;
    const int w = tid >> 6;
    const int lane = tid & 63;
    const int m = lane & 15;
    const int quad = lane >> 4;
    const int row0 = blockIdx.x * 16;
    const int t0 = w * 2;                       // this wave's sim t-tiles

    // --- h: every wave loads the same 16 rows (L1 absorbs the 4x replay)
    const float* hrow = h + (size_t)(row0 + m) * 256 + quad * 8;
    float4 hv[16];
    #pragma unroll
    for (int c = 0; c < 8; c++) {
        hv[c * 2 + 0] = *(const float4*)(hrow + c * 32);
        hv[c * 2 + 1] = *(const float4*)(hrow + c * 32 + 4);
    }
    float s = 0.f;
    #pragma unroll
    for (int i = 0; i < 16; i++) {
        s += hv[i].x * hv[i].x + hv[i].y * hv[i].y
           + hv[i].z * hv[i].z + hv[i].w * hv[i].w;
    }
    f16x8 A[8];
    #pragma unroll
    for (int c = 0; c < 8; c++) {
        A[c][0] = (_Float16)hv[c*2+0].x; A[c][1] = (_Float16)hv[c*2+0].y;
        A[c][2] = (_Float16)hv[c*2+0].z; A[c][3] = (_Float16)hv[c*2+0].w;
        A[c][4] = (_Float16)hv[c*2+1].x; A[c][5] = (_Float16)hv[c*2+1].y;
        A[c][6] = (_Float16)hv[c*2+1].z; A[c][7] = (_Float16)hv[c*2+1].w;
    }
    s += __shfl_xor(s, 16, 64);
    s += __shfl_xor(s, 32, 64);
    const float inv = 1.0f / fmaxf(sqrtf(s), EPS);   // 1/||h[row m]||

    // softmax slope per output row r; log2e folded in: p = exp2((sim-mx)*tinv)
    float tinv[4];
    #pragma unroll
    for (int r = 0; r < 4; r++)
        tinv[r] = TAU_INV * 1.44269504f * __shfl(inv, quad * 4 + r, 64);

    // --- sim GEMM for this wave's 2 t-tiles (32 of 128 K-columns)
    const f16x8* sB = (const f16x8*)simB;
    f32x4 acc[2] = {};
    #pragma unroll
    for (int tt = 0; tt < 2; tt++) {
        f16x8 Bt[8];
        #pragma unroll
        for (int c = 0; c < 8; c++) Bt[c] = sB[((t0 + tt) * 8 + c) * 64 + lane];
        #pragma unroll
        for (int c = 0; c < 8; c++)
            acc[tt] = __builtin_amdgcn_mfma_f32_16x16x32_f16(A[c], Bt[c], acc[tt], 0, 0, 0);
    }

    const float sc0 = scale[t0 * 16 + m];
    const float sc1 = scale[(t0 + 1) * 16 + m];

    // --- per-row partial softmax over this wave's 32 columns
    float e0[4], e1[4], mxw[4];
    #pragma unroll
    for (int r = 0; r < 4; r++) {
        float mx = fmaxf(acc[0][r], acc[1][r]);
        #pragma unroll
        for (int msk = 1; msk < 16; msk <<= 1) mx = fmaxf(mx, __shfl_xor(mx, msk, 64));
        e0[r] = __builtin_amdgcn_exp2f((acc[0][r] - mx) * tinv[r]);
        e1[r] = __builtin_amdgcn_exp2f((acc[1][r] - mx) * tinv[r]);
        float sp = e0[r] + e1[r];
        #pragma unroll
        for (int msk = 1; msk < 16; msk <<= 1) sp += __shfl_xor(sp, msk, 64);
        mxw[r] = mx;
        if (m == 0) { pmx[w][quad * 4 + r] = mx; psum[w][quad * 4 + r] = sp; }
    }
    __syncthreads();

    // --- LSE merge across the 4 waves + p store + pbuf (= p * proto_scale)
    #pragma unroll
    for (int r = 0; r < 4; r++) {
        const int row = quad * 4 + r;
        const float m0 = pmx[0][row], m1 = pmx[1][row];
        const float m2 = pmx[2][row], m3 = pmx[3][row];
        const float mg = fmaxf(fmaxf(m0, m1), fmaxf(m2, m3));
        const float sg =
              psum[0][row] * __builtin_amdgcn_exp2f((m0 - mg) * tinv[r])
            + psum[1][row] * __builtin_amdgcn_exp2f((m1 - mg) * tinv[r])
            + psum[2][row] * __builtin_amdgcn_exp2f((m2 - mg) * tinv[r])
            + psum[3][row] * __builtin_amdgcn_exp2f((m3 - mg) * tinv[r]);
        const float fac = __builtin_amdgcn_exp2f((mxw[r] - mg) * tinv[r]) / sg;
        const float p0 = e0[r] * fac;
        const float p1 = e1[r] * fac;
        float* po = out_p + (size_t)(row0 + row) * 128;
        po[t0 * 16 + m] = p0;
        po[(t0 + 1) * 16 + m] = p1;
        pbuf[row * PB_STRIDE + t0 * 16 + m] = (_Float16)(p0 * sc0);
        pbuf[row * PB_STRIDE + (t0 + 1) * 16 + m] = (_Float16)(p1 * sc1);
    }
    __syncthreads();

    // --- z GEMM for this wave's 4 dt-tiles; A = full P rows from LDS
    f16x8 Ap[4];
    #pragma unroll
    for (int kc = 0; kc < 4; kc++)
        Ap[kc] = *(const f16x8*)&pbuf[m * PB_STRIDE + kc * 32 + quad * 8];

    const f16x8* zB8 = (const f16x8*)zB;
    #pragma unroll
    for (int i = 0; i < 4; i++) {
        const int dt = w * 4 + i;
        f16x8 Bz[4];
        #pragma unroll
        for (int kc = 0; kc < 4; kc++) Bz[kc] = zB8[(dt * 4 + kc) * 64 + lane];
        f32x4 zc = {};
        #pragma unroll
        for (int kc = 0; kc < 4; kc++)
            zc = __builtin_amdgcn_mfma_f32_16x16x32_f16(Ap[kc], Bz[kc], zc, 0, 0, 0);
        #pragma unroll
        for (int r = 0; r < 4; r++)
            out_z[(size_t)(row0 + quad * 4 + r) * 256 + dt * 16 + m] = zc[r];
    }
}

// ---------------------------------------------------------------------------
extern "C" void kernel_launch(void* const* d_in, const int* in_sizes, int n_in,
                              void* d_out, int out_size, void* d_ws, size_t ws_size,
                              hipStream_t stream) {
    const float* h_in  = (const float*)d_in[0];   // (B,P,D) fp32, B*P=65536, D=256
    const float* proto = (const float*)d_in[1];   // (K,D) fp32, K=128

    const int M = in_sizes[0] / 256;              // 65536 rows

    // ws: scale[128] f32 (1 KiB slot) | simB (64 KiB) | zB (64 KiB)
    float*     scale = (float*)d_ws;
    _Float16*  simB  = (_Float16*)((char*)d_ws + 1024);
    _Float16*  zB    = (_Float16*)((char*)d_ws + 1024 + 65536);

    float* out_p = (float*)d_out;                 // (M,128)
    float* out_z = out_p + (size_t)M * 128;       // (M,256)

    k_prep<<<dim3(128), dim3(64), 0, stream>>>(proto, scale);
    k_frag<<<dim3(128), dim3(64), 0, stream>>>(proto, scale, simB, zB);
    k_main<<<dim3(M / 16), dim3(256), 0, stream>>>(h_in, scale, simB, zB,
                                                   out_p, out_z);
}

// Round 5
// 160.343 us; speedup vs baseline: 1.2007x; 1.2007x over previous
//
#include <hip/hip_runtime.h>
#include <math.h>

// SoftCodebook fused kernel v7 for MI355X (gfx950).
// p = softmax( (h/||h||) @ (proto/||proto||)^T / 0.1 ),  z = p @ proto
// v7: kill the per-wave VMEM chain (v2-v6 all latency-bound at 61-84us, ~1
// load in flight/wave, scheduler defeats SW pipelining). Codebook fragment
// images (128 KB) are staged ONCE per CU into LDS; all 128 B-fragment reads
// per wave become ds_read_b128 (lgkmcnt, short latency, compiler schedules
// near-optimally). Per-wave global ops: 16 h loads (one burst) + stores.
//   grid 256 x 1024 thr (16 waves, 4/SIMD, 1 block/CU), 256 rows/block.
//   LDS 136192 B: simB 64K | zB 64K | tail; p-transpose buffer overlays the
//   simB region (barrier 2 after sim GEMM makes this safe).

#define EPS 1e-12f
#define TAU_INV 10.0f

typedef _Float16 f16x8 __attribute__((ext_vector_type(8)));
typedef float f32x4 __attribute__((ext_vector_type(4)));
typedef const __attribute__((address_space(1))) void* gptr_t;
typedef __attribute__((address_space(3))) void* lptr_t;

#define PB_STRIDE 136   // halves per pbuf row: 272 B = 17*16 (16B-aligned rows)

// ---------------------------------------------------------------------------
// k_prep: per-prototype L2 norm -> scale[128].  grid 128 x 64.
__global__ void k_prep(const float* __restrict__ proto, float* __restrict__ scale) {
    const int kp = blockIdx.x;
    const int lane = threadIdx.x;
    const float4 v = ((const float4*)(proto + kp * 256))[lane];
    float s = v.x * v.x + v.y * v.y + v.z * v.z + v.w * v.w;
    #pragma unroll
    for (int msk = 1; msk < 64; msk <<= 1) s += __shfl_xor(s, msk, 64);
    if (lane == 0) scale[kp] = fmaxf(sqrtf(s), EPS);
}

// ---------------------------------------------------------------------------
// k_frag: build per-lane B-fragment images (f16 cbar) in ws.  grid 128 x 64.
//   simB[(t*8+c)*512 + lane*8 + j] = cbar[t*16+m][c*32+q*8+j]   (sim B)
//   zB [(dt*4+kc)*512 + lane*8 + j] = cbar[kc*32+q*8+j][dt*16+m] (z  B)
// where m = lane&15, q = lane>>4 (matches mfma_f32_16x16x32_f16 B layout).
// simB and zB are CONTIGUOUS in ws -> k_main stages both with one base ptr.
__global__ void k_frag(const float* __restrict__ proto,
                       const float* __restrict__ scale,
                       _Float16* __restrict__ simB, _Float16* __restrict__ zB) {
    const int b = blockIdx.x;
    const int lane = threadIdx.x;
    const int m = lane & 15, q = lane >> 4;
    _Float16 r[8];
    if (b < 64) {
        const int t = b >> 3, c = b & 7;
        const int kp = t * 16 + m;
        const float inv = 1.0f / scale[kp];
        const float* src = proto + (size_t)kp * 256 + c * 32 + q * 8;
        #pragma unroll
        for (int j = 0; j < 8; j++) r[j] = (_Float16)(src[j] * inv);
        *(f16x8*)(simB + ((size_t)b * 64 + lane) * 8) = *(const f16x8*)r;
    } else {
        const int b2 = b - 64;
        const int dt = b2 >> 2, kc = b2 & 3;
        #pragma unroll
        for (int j = 0; j < 8; j++) {
            const int kk = kc * 32 + q * 8 + j;
            r[j] = (_Float16)(proto[(size_t)kk * 256 + dt * 16 + m] / scale[kk]);
        }
        *(f16x8*)(zB + ((size_t)b2 * 64 + lane) * 8) = *(const f16x8*)r;
    }
}

// ---------------------------------------------------------------------------
// k_main: 1024 threads = 16 waves, each owns 16 rows; grid = M/256 = 256.
__global__ __launch_bounds__(1024, 4) void k_main(
    const float* __restrict__ h,
    const float* __restrict__ scale,
    const char* __restrict__ cbimg,     // simB|zB fragment images, 131072 B
    float* __restrict__ out_p,
    float* __restrict__ out_z) {

    // halves: simB [0,32768) | zB [32768,65536) | tail [65536,68096)
    __shared__ _Float16 lds[68096];     // 136192 B

    const int tid = threadIdx.x;
    const int w = tid >> 6;             // 0..15
    const int lane = tid & 63;
    const int m = lane & 15;
    const int quad = lane >> 4;
    const int row0 = blockIdx.x * 256 + w * 16;

    // --- h burst first (oldest vmcnt -> sumsq can start at vmcnt(8))
    const float* hrow = h + (size_t)(row0 + m) * 256 + quad * 8;
    float4 hv[16];
    #pragma unroll
    for (int c = 0; c < 8; c++) {
        hv[c * 2 + 0] = *(const float4*)(hrow + c * 32);
        hv[c * 2 + 1] = *(const float4*)(hrow + c * 32 + 4);
    }

    // --- stage codebook images: 128 x 1KB chunks, 8 per wave, async -> LDS
    #pragma unroll
    for (int it = 0; it < 8; ++it) {
        const int c = w * 8 + it;
        __builtin_amdgcn_global_load_lds((gptr_t)(cbimg + c * 1024 + lane * 16),
                                         (lptr_t)((char*)lds + c * 1024), 16, 0, 0);
    }

    // --- sumsq + f16 convert (overlaps staging latency)
    float s = 0.f;
    #pragma unroll
    for (int i = 0; i < 16; i++) {
        s += hv[i].x * hv[i].x + hv[i].y * hv[i].y
           + hv[i].z * hv[i].z + hv[i].w * hv[i].w;
    }
    f16x8 A[8];
    #pragma unroll
    for (int c = 0; c < 8; c++) {
        A[c][0] = (_Float16)hv[c*2+0].x; A[c][1] = (_Float16)hv[c*2+0].y;
        A[c][2] = (_Float16)hv[c*2+0].z; A[c][3] = (_Float16)hv[c*2+0].w;
        A[c][4] = (_Float16)hv[c*2+1].x; A[c][5] = (_Float16)hv[c*2+1].y;
        A[c][6] = (_Float16)hv[c*2+1].z; A[c][7] = (_Float16)hv[c*2+1].w;
    }
    s += __shfl_xor(s, 16, 64);
    s += __shfl_xor(s, 32, 64);
    const float inv = 1.0f / fmaxf(sqrtf(s), EPS);   // 1/||h[row m]||

    // softmax slope per output row r; log2e folded in: p = exp2((sim-mx)*tinv)
    float tinv[4];
    #pragma unroll
    for (int r = 0; r < 4; r++)
        tinv[r] = TAU_INV * 1.44269504f * __shfl(inv, quad * 4 + r, 64);

    __syncthreads();    // staging resident (drains vmcnt+lgkmcnt)

    // --- sim GEMM from LDS: acc[t][row r] = h[row]·cbar[t*16+m]
    const _Float16* sBl = lds;
    f32x4 acc[8] = {};
    #pragma unroll
    for (int t = 0; t < 8; t++) {
        f16x8 Bt[8];
        #pragma unroll
        for (int c = 0; c < 8; c++)
            Bt[c] = *(const f16x8*)&sBl[(t * 8 + c) * 512 + lane * 8];
        #pragma unroll
        for (int c = 0; c < 8; c++)
            acc[t] = __builtin_amdgcn_mfma_f32_16x16x32_f16(A[c], Bt[c], acc[t], 0, 0, 0);
    }

    // prototype scales for the z-path A operand (proto = cbar * scale)
    float sc_l[8];
    #pragma unroll
    for (int t = 0; t < 8; t++) sc_l[t] = scale[t * 16 + m];

    __syncthreads();    // ALL sim reads done -> pbuf may overlay simB region

    // wave-private p-transpose buffer: waves 0..14 inside simB region, 15 in tail
    _Float16* pb = lds + (w == 15 ? 65536 : w * (16 * PB_STRIDE));

    // --- softmax over K=128 per row; norm folded into slope tinv[r]
    #pragma unroll
    for (int r = 0; r < 4; r++) {
        float mx = acc[0][r];
        #pragma unroll
        for (int t = 1; t < 8; t++) mx = fmaxf(mx, acc[t][r]);
        #pragma unroll
        for (int msk = 1; msk < 16; msk <<= 1) mx = fmaxf(mx, __shfl_xor(mx, msk, 64));
        float e[8];
        float sum = 0.f;
        #pragma unroll
        for (int t = 0; t < 8; t++) {
            e[t] = __builtin_amdgcn_exp2f((acc[t][r] - mx) * tinv[r]);
            sum += e[t];
        }
        #pragma unroll
        for (int msk = 1; msk < 16; msk <<= 1) sum += __shfl_xor(sum, msk, 64);
        const float rs = 1.0f / sum;
        const int grow = row0 + quad * 4 + r;
        float* po = out_p + (size_t)grow * 128;
        const int prow = quad * 4 + r;
        #pragma unroll
        for (int t = 0; t < 8; t++) {
            const float p = e[t] * rs;
            po[t * 16 + m] = p;
            pb[prow * PB_STRIDE + t * 16 + m] = (_Float16)(p * sc_l[t]);
        }
    }

    // --- z GEMM: A = (p*scale) from wave-private pbuf (same-wave lgkmcnt order),
    // B from LDS-resident zB fragments.
    f16x8 Ap[4];
    #pragma unroll
    for (int kc = 0; kc < 4; kc++)
        Ap[kc] = *(const f16x8*)&pb[m * PB_STRIDE + kc * 32 + quad * 8];

    const _Float16* zBl = lds + 32768;
    #pragma unroll
    for (int dt = 0; dt < 16; dt++) {
        f16x8 Bz[4];
        #pragma unroll
        for (int kc = 0; kc < 4; kc++)
            Bz[kc] = *(const f16x8*)&zBl[(dt * 4 + kc) * 512 + lane * 8];
        f32x4 zc = {};
        #pragma unroll
        for (int kc = 0; kc < 4; kc++)
            zc = __builtin_amdgcn_mfma_f32_16x16x32_f16(Ap[kc], Bz[kc], zc, 0, 0, 0);
        #pragma unroll
        for (int r = 0; r < 4; r++)
            out_z[(size_t)(row0 + quad * 4 + r) * 256 + dt * 16 + m] = zc[r];
    }
}

// ---------------------------------------------------------------------------
extern "C" void kernel_launch(void* const* d_in, const int* in_sizes, int n_in,
                              void* d_out, int out_size, void* d_ws, size_t ws_size,
                              hipStream_t stream) {
    const float* h_in  = (const float*)d_in[0];   // (B,P,D) fp32, B*P=65536, D=256
    const float* proto = (const float*)d_in[1];   // (K,D) fp32, K=128

    const int M = in_sizes[0] / 256;              // 65536 rows

    // ws: scale[128] f32 (1 KiB slot) | simB (64 KiB) | zB (64 KiB), contiguous
    float*     scale = (float*)d_ws;
    _Float16*  simB  = (_Float16*)((char*)d_ws + 1024);
    _Float16*  zB    = (_Float16*)((char*)d_ws + 1024 + 65536);
    const char* cbimg = (const char*)d_ws + 1024;

    float* out_p = (float*)d_out;                 // (M,128)
    float* out_z = out_p + (size_t)M * 128;       // (M,256)

    k_prep<<<dim3(128), dim3(64), 0, stream>>>(proto, scale);
    k_frag<<<dim3(128), dim3(64), 0, stream>>>(proto, scale, simB, zB);
    k_main<<<dim3(M / 256), dim3(1024), 0, stream>>>(h_in, scale, cbimg,
                                                     out_p, out_z);
}

// Round 6
// 157.100 us; speedup vs baseline: 1.2255x; 1.0206x over previous
//
#include <hip/hip_runtime.h>
#include <math.h>

// SoftCodebook fused kernel v8 for MI355X (gfx950).
// p = softmax( (h/||h||) @ (proto/||proto||)^T / 0.1 ),  z = p @ proto
// v8 = v7 datapath (codebook fragment images LDS-resident, ds_read_b128 ->
// MFMA, wave-private rows, 2 barriers) with the WHOLE prep pipeline folded in:
// each block builds the fragment images directly in its own LDS from proto
// (L2-broadcast 128 KB), computes prototype norms in-block (8 lanes/proto,
// shfl-reduce), norms kept in an LDS array. Eliminates k_prep + k_frag
// launches (serialized, latency-bound, uncoalesced z-branch) and the ws
// round-trip -- evidence: v7's dispatch table shows k_main < 59us while
// dur_us-k_main ~ 100us fixed, of which ~40us was prep kernels + gaps.
//   grid 256 x 1024 thr (16 waves, 4/SIMD, 1 block/CU), 256 rows/block.
//   LDS: simB 64K | zB 64K | tail (wave15 pbuf) + norms; pbuf overlays simB
//   after barrier 2 (all sim reads done), exactly as v7.

#define EPS 1e-12f
#define TAU_INV 10.0f

typedef _Float16 f16x8 __attribute__((ext_vector_type(8)));
typedef float f32x4 __attribute__((ext_vector_type(4)));

#define PB_STRIDE 136   // halves per pbuf row: 272 B = 17*16 (16B-aligned rows)

// ---------------------------------------------------------------------------
// k_main: 1024 threads = 16 waves, each owns 16 rows; grid = M/256 = 256.
__global__ __launch_bounds__(1024, 4) void k_main(
    const float* __restrict__ h,
    const float* __restrict__ proto,    // (K=128, D=256) fp32
    float* __restrict__ out_p,
    float* __restrict__ out_z) {

    // halves: simB [0,32768) | zB [32768,65536) | tail [65536,68096)
    __shared__ _Float16 lds[68096];     // 136192 B
    __shared__ float norms[128];        // prototype L2 norms

    const int tid = threadIdx.x;
    const int w = tid >> 6;             // 0..15
    const int lane = tid & 63;
    const int m = lane & 15;
    const int quad = lane >> 4;
    const int row0 = blockIdx.x * 256 + w * 16;

    // --- h burst first (HBM latency hides under the LDS build phase)
    const float* hrow = h + (size_t)(row0 + m) * 256 + quad * 8;
    float4 hv[16];
    #pragma unroll
    for (int c = 0; c < 8; c++) {
        hv[c * 2 + 0] = *(const float4*)(hrow + c * 32);
        hv[c * 2 + 1] = *(const float4*)(hrow + c * 32 + 4);
    }

    // =======================================================================
    // In-LDS codebook build. Wave w owns protos kp = 8w .. 8w+7;
    // 8 lanes per proto, each lane owns 32 d-values: d = (lane&7)*32 + 0..31.
    {
        const int kp = w * 8 + (lane >> 3);
        const int l8 = lane & 7;
        const float* psrc = proto + (size_t)kp * 256 + l8 * 32;
        float4 pv[8];
        #pragma unroll
        for (int i = 0; i < 8; i++) pv[i] = *(const float4*)(psrc + i * 4);

        float ss = 0.f;
        #pragma unroll
        for (int i = 0; i < 8; i++) {
            ss += pv[i].x * pv[i].x + pv[i].y * pv[i].y
                + pv[i].z * pv[i].z + pv[i].w * pv[i].w;
        }
        ss += __shfl_xor(ss, 1, 64);
        ss += __shfl_xor(ss, 2, 64);
        ss += __shfl_xor(ss, 4, 64);
        const float nrm = fmaxf(sqrtf(ss), EPS);      // proto = cbar * nrm
        const float inv = 1.0f / nrm;
        if (l8 == 0) norms[kp] = nrm;

        _Float16 cb[32];
        #pragma unroll
        for (int i = 0; i < 8; i++) {
            cb[i*4+0] = (_Float16)(pv[i].x * inv);
            cb[i*4+1] = (_Float16)(pv[i].y * inv);
            cb[i*4+2] = (_Float16)(pv[i].z * inv);
            cb[i*4+3] = (_Float16)(pv[i].w * inv);
        }

        // sim image: simB[(t*8+c)*512 + (q*16+mm)*8 + j] = cbar[kp][c*32+q*8+j]
        //   t=kp>>4, mm=kp&15, c=l8 (this lane's chunk), q=0..3, j=0..7
        {
            const int t = kp >> 4, mm = kp & 15;
            _Float16* base = lds + (t * 8 + l8) * 512 + mm * 8;
            #pragma unroll
            for (int q = 0; q < 4; q++)
                *(f16x8*)(base + q * 128) = *(const f16x8*)&cb[q * 8];
        }

        // z image: zB[(dt*4+kc)*512 + (qz*16+mz)*8 + jz] = cbar[kp][dt*16+mz]
        //   kc=kp>>5, qz=(kp>>3)&3, jz=kp&7; lane's d = l8*32+dd -> dt=l8*2+(dd>>4)
        {
            const int kc = kp >> 5, qz = (kp >> 3) & 3, jz = kp & 7;
            _Float16* zb = lds + 32768 + kc * 512 + qz * 128 + jz;
            #pragma unroll
            for (int dd = 0; dd < 32; dd++) {
                const int dt = l8 * 2 + (dd >> 4);
                const int mz = dd & 15;
                zb[(size_t)dt * 2048 + mz * 8] = cb[dd];
            }
        }
    }

    // --- h sumsq + f16 convert (overlaps proto/h load latency)
    float s = 0.f;
    #pragma unroll
    for (int i = 0; i < 16; i++) {
        s += hv[i].x * hv[i].x + hv[i].y * hv[i].y
           + hv[i].z * hv[i].z + hv[i].w * hv[i].w;
    }
    f16x8 A[8];
    #pragma unroll
    for (int c = 0; c < 8; c++) {
        A[c][0] = (_Float16)hv[c*2+0].x; A[c][1] = (_Float16)hv[c*2+0].y;
        A[c][2] = (_Float16)hv[c*2+0].z; A[c][3] = (_Float16)hv[c*2+0].w;
        A[c][4] = (_Float16)hv[c*2+1].x; A[c][5] = (_Float16)hv[c*2+1].y;
        A[c][6] = (_Float16)hv[c*2+1].z; A[c][7] = (_Float16)hv[c*2+1].w;
    }
    s += __shfl_xor(s, 16, 64);
    s += __shfl_xor(s, 32, 64);
    const float inv = 1.0f / fmaxf(sqrtf(s), EPS);   // 1/||h[row m]||

    // softmax slope per output row r; log2e folded in: p = exp2((sim-mx)*tinv)
    float tinv[4];
    #pragma unroll
    for (int r = 0; r < 4; r++)
        tinv[r] = TAU_INV * 1.44269504f * __shfl(inv, quad * 4 + r, 64);

    __syncthreads();    // codebook images + norms resident

    // --- sim GEMM from LDS: acc[t][row r] = h[row]·cbar[t*16+m]
    const _Float16* sBl = lds;
    f32x4 acc[8] = {};
    #pragma unroll
    for (int t = 0; t < 8; t++) {
        f16x8 Bt[8];
        #pragma unroll
        for (int c = 0; c < 8; c++)
            Bt[c] = *(const f16x8*)&sBl[(t * 8 + c) * 512 + lane * 8];
        #pragma unroll
        for (int c = 0; c < 8; c++)
            acc[t] = __builtin_amdgcn_mfma_f32_16x16x32_f16(A[c], Bt[c], acc[t], 0, 0, 0);
    }

    // prototype scales for the z-path A operand (proto = cbar * norm), from LDS
    float sc_l[8];
    #pragma unroll
    for (int t = 0; t < 8; t++) sc_l[t] = norms[t * 16 + m];

    __syncthreads();    // ALL sim reads done -> pbuf may overlay simB region

    // wave-private p-transpose buffer: waves 0..14 inside simB region, 15 in tail
    _Float16* pb = lds + (w == 15 ? 65536 : w * (16 * PB_STRIDE));

    // --- softmax over K=128 per row; norm folded into slope tinv[r]
    #pragma unroll
    for (int r = 0; r < 4; r++) {
        float mx = acc[0][r];
        #pragma unroll
        for (int t = 1; t < 8; t++) mx = fmaxf(mx, acc[t][r]);
        #pragma unroll
        for (int msk = 1; msk < 16; msk <<= 1) mx = fmaxf(mx, __shfl_xor(mx, msk, 64));
        float e[8];
        float sum = 0.f;
        #pragma unroll
        for (int t = 0; t < 8; t++) {
            e[t] = __builtin_amdgcn_exp2f((acc[t][r] - mx) * tinv[r]);
            sum += e[t];
        }
        #pragma unroll
        for (int msk = 1; msk < 16; msk <<= 1) sum += __shfl_xor(sum, msk, 64);
        const float rs = 1.0f / sum;
        const int grow = row0 + quad * 4 + r;
        float* po = out_p + (size_t)grow * 128;
        const int prow = quad * 4 + r;
        #pragma unroll
        for (int t = 0; t < 8; t++) {
            const float p = e[t] * rs;
            po[t * 16 + m] = p;
            pb[prow * PB_STRIDE + t * 16 + m] = (_Float16)(p * sc_l[t]);
        }
    }

    // --- z GEMM: A = (p*scale) from wave-private pbuf (same-wave lgkmcnt order),
    // B from LDS-resident zB fragments.
    f16x8 Ap[4];
    #pragma unroll
    for (int kc = 0; kc < 4; kc++)
        Ap[kc] = *(const f16x8*)&pb[m * PB_STRIDE + kc * 32 + quad * 8];

    const _Float16* zBl = lds + 32768;
    #pragma unroll
    for (int dt = 0; dt < 16; dt++) {
        f16x8 Bz[4];
        #pragma unroll
        for (int kc = 0; kc < 4; kc++)
            Bz[kc] = *(const f16x8*)&zBl[(dt * 4 + kc) * 512 + lane * 8];
        f32x4 zc = {};
        #pragma unroll
        for (int kc = 0; kc < 4; kc++)
            zc = __builtin_amdgcn_mfma_f32_16x16x32_f16(Ap[kc], Bz[kc], zc, 0, 0, 0);
        #pragma unroll
        for (int r = 0; r < 4; r++)
            out_z[(size_t)(row0 + quad * 4 + r) * 256 + dt * 16 + m] = zc[r];
    }
}

// ---------------------------------------------------------------------------
extern "C" void kernel_launch(void* const* d_in, const int* in_sizes, int n_in,
                              void* d_out, int out_size, void* d_ws, size_t ws_size,
                              hipStream_t stream) {
    const float* h_in  = (const float*)d_in[0];   // (B,P,D) fp32, B*P=65536, D=256
    const float* proto = (const float*)d_in[1];   // (K,D) fp32, K=128

    const int M = in_sizes[0] / 256;              // 65536 rows

    float* out_p = (float*)d_out;                 // (M,128)
    float* out_z = out_p + (size_t)M * 128;       // (M,256)

    k_main<<<dim3(M / 256), dim3(1024), 0, stream>>>(h_in, proto, out_p, out_z);
}